// Round 7
// baseline (144.239 us; speedup 1.0000x reference)
//
#include <hip/hip_runtime.h>
#include <math.h>

#define Bdim 4
#define Sdim 4096
#define Gdim 4
#define Ddim 256
#define Ndim 128
#define NTOK (Bdim*Sdim*Gdim)      // 65536 tokens
#define CHUNKS 128
#define CLEN (Sdim/CHUNKS)         // 32 steps per chunk == M-tile s-span
#define NCHAN (Bdim*Gdim*Ndim)     // 2048 scan channels
#define NTILE (Bdim*CHUNKS)        // 512 M-tiles of 128 tokens

typedef unsigned short u16;
typedef unsigned int   u32;
typedef unsigned char  u8;
typedef __attribute__((ext_vector_type(8))) _Float16 f16x8;
typedef __attribute__((ext_vector_type(4))) _Float16 f16x4;
typedef __attribute__((ext_vector_type(4))) float f32x4;

#define GLOBAL_AS __attribute__((address_space(1)))
#define LDS_AS    __attribute__((address_space(3)))

__device__ __forceinline__ void gl_lds16(const void* g, void* l) {
    __builtin_amdgcn_global_load_lds((const GLOBAL_AS u32*)g, (LDS_AS u32*)l, 16, 0, 0);
}

union HU { _Float16 h; u16 u; };
__device__ __forceinline__ u16 f2h(float f) { HU c; c.h = (_Float16)f; return c.u; }
__device__ __forceinline__ float h2f(u16 u) { HU c; c.u = u; return (float)c.h; }

// ---------------------------------------------------------------------------
// Kernel 1: dt projection (fp32) + d_out zero-fill + weight prep, one launch.
// Blocks [0,16384): dt for 4 tokens each + zero 8 KB of out.
// Blocks [16384,16896): f16 weight prep.
// ---------------------------------------------------------------------------
__global__ __launch_bounds__(256) void dt_prep_zero(
    const float* __restrict__ xr, const float* __restrict__ xi,
    const float* __restrict__ dtw, const float* __restrict__ dtb,
    const float* __restrict__ Bwr, const float* __restrict__ Bwi,
    const float* __restrict__ Cwr, const float* __restrict__ Cwi,
    float* __restrict__ dtm, float* __restrict__ dtp,
    u16* __restrict__ WbxH, u16* __restrict__ WyH,
    float* __restrict__ out)
{
    const int tid = threadIdx.x;
    if (blockIdx.x >= 16384) {                       // weight prep
        const int idx = (blockIdx.x - 16384) * 256 + tid;   // 0..131071
        {
            const int n = idx >> 9, k = idx & 511;
            float v;
            if (n < 128) v = (k < 256) ? Bwr[n * 256 + k] : -Bwi[n * 256 + (k - 256)];
            else         v = (k < 256) ? Bwi[(n - 128) * 256 + k] : Bwr[(n - 128) * 256 + (k - 256)];
            WbxH[idx] = f2h(v);
        }
        {
            const int d = idx >> 8, k = idx & 255;
            float v;
            if (d < 256) v = (k < 128) ? Cwr[d * 128 + k] : -Cwi[d * 128 + (k - 128)];
            else         v = (k < 128) ? Cwi[(d - 256) * 128 + k] : Cwr[(d - 256) * 128 + (k - 128)];
            WyH[idx] = f2h(v);
        }
        return;
    }

    // zero 2048 floats of out per block (16384 * 8 KB = 128 MiB total)
    {
        const float4 z = make_float4(0.f, 0.f, 0.f, 0.f);
        float* o = out + (size_t)blockIdx.x * 2048 + tid * 8;
        *(float4*)(o)     = z;
        *(float4*)(o + 4) = z;
    }

    const int gtid = blockIdx.x * 256 + tid;
    const int tok  = gtid >> 6;
    const int lane = gtid & 63;

    const float4 a  = *(const float4*)(xr  + (size_t)tok * Ddim + lane * 4);
    const float4 b4 = *(const float4*)(xi  + (size_t)tok * Ddim + lane * 4);
    const float4 c0 = *(const float4*)(dtw +   0 + lane * 4);
    const float4 d0 = *(const float4*)(dtw + 256 + lane * 4);
    const float4 c1 = *(const float4*)(dtw + 512 + lane * 4);
    const float4 d1 = *(const float4*)(dtw + 768 + lane * 4);

    float r0 = a.x*c0.x + a.y*c0.y + a.z*c0.z + a.w*c0.w
             + b4.x*d0.x + b4.y*d0.y + b4.z*d0.z + b4.w*d0.w;
    float r1 = a.x*c1.x + a.y*c1.y + a.z*c1.z + a.w*c1.w
             + b4.x*d1.x + b4.y*d1.y + b4.z*d1.z + b4.w*d1.w;
    #pragma unroll
    for (int off = 32; off; off >>= 1) {
        r0 += __shfl_down(r0, off);
        r1 += __shfl_down(r1, off);
    }
    if (lane == 0) {
        float m = expf(r0 + dtb[0]); m = fminf(fmaxf(m, 1e-4f), 2.0f);
        float p = expf(r1 + dtb[1]); p = fminf(fmaxf(p, 1e-4f), 2.0f);
        dtm[tok] = m;
        dtp[tok] = p;
    }
}

// ---------------------------------------------------------------------------
// Kernel 2: f64 cumsum of dt per (b,g) + alive flags + scan flag/ticket reset.
// ---------------------------------------------------------------------------
__global__ __launch_bounds__(256) void cumsum_kernel(
    const float* __restrict__ dtm, const float* __restrict__ dtp,
    const float* __restrict__ logAmag,
    double* __restrict__ cumM, double* __restrict__ cumP,
    u8* __restrict__ aliveF, u32* __restrict__ flags, u32* __restrict__ ticket)
{
    const int bg = blockIdx.x, b = bg >> 2, g = bg & 3;
    const int t = threadIdx.x, lane = t & 63, wid = t >> 6;

    // reset lookback flags (layout flags[c][16bg]) and tickets
    if (t < CHUNKS) flags[t * 16 + bg] = 0;
    if (t == 128)   ticket[bg] = 0;

    // min_n softplus(log_A_mag[g,n])
    __shared__ float sws[4];
    float sp = 1e30f;
    if (t < 128) sp = log1pf(expf(logAmag[g * Ndim + t]));
    #pragma unroll
    for (int off = 32; off; off >>= 1) sp = fminf(sp, __shfl_down(sp, off));
    if (lane == 0) sws[wid] = sp;
    __syncthreads();
    const float minsp = fminf(fminf(sws[0], sws[1]), fminf(sws[2], sws[3]));
    __syncthreads();

    const size_t base = (size_t)b * Sdim * Gdim + g;
    double lm[16], lp[16], sm = 0.0, sp2 = 0.0;
    #pragma unroll
    for (int j = 0; j < 16; ++j) {
        const size_t tok = base + (size_t)(t * 16 + j) * Gdim;
        sm  += (double)dtm[tok]; lm[j] = sm;
        sp2 += (double)dtp[tok]; lp[j] = sp2;
    }
    double im = sm, ip = sp2;
    #pragma unroll
    for (int off = 1; off < 64; off <<= 1) {
        double vm = __shfl_up(im, off);
        double vp = __shfl_up(ip, off);
        if (lane >= off) { im += vm; ip += vp; }
    }
    __shared__ double wtm[4], wtp[4];
    if (lane == 63) { wtm[wid] = im; wtp[wid] = ip; }
    __syncthreads();
    double bm = im - sm, bp = ip - sp2;
    for (int w = 0; w < wid; ++w) { bm += wtm[w]; bp += wtp[w]; }
    #pragma unroll
    for (int j = 0; j < 16; ++j) {
        const size_t tok = base + (size_t)(t * 16 + j) * Gdim;
        cumM[tok] = bm + lm[j];
        cumP[tok] = bp + lp[j];
    }
    if ((t & 1) == 0) {   // chunk c = t/2 starts at this thread's j=0
        const int c = t >> 1;
        const double cm0 = bm + lm[0];               // inclusive cumM at s=32c
        aliveF[(size_t)(b * CHUNKS + c) * 4 + g] =
            ((double)minsp * cm0 <= 106.0) ? 1 : 0;
    }
}

// ---------------------------------------------------------------------------
// Kernel 3: GEMM 1 (MFMA f16): bx = (xcat . Wbx^T) * dt_mag  (f16, alive only)
// ---------------------------------------------------------------------------
__global__ __launch_bounds__(256) void gemm_bx_mfma(
    const float* __restrict__ xr, const float* __restrict__ xi,
    const u16* __restrict__ Wh, const float* __restrict__ dtm,
    const u32* __restrict__ aliveT,
    u16* __restrict__ bxh)
{
    const int i0 = blockIdx.x;                       // 0..1023
    const int wg = (i0 & 7) * 128 + (i0 >> 3);       // bijective XCD chunking
    if (aliveT[wg >> 1] == 0) return;

    __shared__ u16 sA[128 * 32], sWh[128 * 32];
    __shared__ float sDtM[128];
    const int tid = threadIdx.x, wave = tid >> 6, lane = tid & 63;
    const size_t m0 = (size_t)(wg >> 1) * 128;
    const int n0 = (wg & 1) * 128;
    const int wm = (wave >> 1) * 64, wn = (wave & 1) * 64;
    f32x4 acc[4][4] = {};
    const int srow = lane >> 2, pslot = lane & 3;

    if (tid < 128) sDtM[tid] = dtm[m0 + tid];

    const int arow = tid >> 3;            // 0..31
    const int acol = (tid & 7) * 4;       // 0..28 within 32-col window
    const int asl  = acol >> 3;
    const int asub = acol & 7;

    #pragma unroll 1
    for (int k0 = 0; k0 < 512; k0 += 32) {
        {   // A: coalesced fp32 load -> f16 ds_write (swizzled)
            const float* xsrc = (k0 < 256) ? xr : xi;
            const int kk = (k0 & 255) + acol;
            #pragma unroll
            for (int i = 0; i < 4; ++i) {
                const int row = arow + 32 * i;
                const float4 v = *(const float4*)(xsrc + (m0 + row) * 256 + kk);
                f16x4 p;
                p[0] = (_Float16)v.x; p[1] = (_Float16)v.y;
                p[2] = (_Float16)v.z; p[3] = (_Float16)v.w;
                *(f16x4*)&sA[row * 32 + (asl ^ ((row >> 1) & 3)) * 8 + asub] = p;
            }
        }
        #pragma unroll
        for (int i = 0; i < 2; ++i) {                // W via global_load_lds
            const int row = wave * 32 + i * 16 + srow;
            const int lslot = pslot ^ ((row >> 1) & 3);
            gl_lds16(Wh + (size_t)(n0 + row) * 512 + k0 + lslot * 8,
                     sWh + row * 32 + pslot * 8);
        }
        __syncthreads();

        const int fr = lane & 15, fs = lane >> 4;
        f16x8 a_[4], w_[4];
        #pragma unroll
        for (int f = 0; f < 4; ++f) {
            const int ra = wm + f * 16 + fr;
            a_[f] = *(const f16x8*)&sA [ra * 32 + (fs ^ ((ra >> 1) & 3)) * 8];
            const int rw = wn + f * 16 + fr;
            w_[f] = *(const f16x8*)&sWh[rw * 32 + (fs ^ ((rw >> 1) & 3)) * 8];
        }
        #pragma unroll
        for (int fm = 0; fm < 4; ++fm)
            #pragma unroll
            for (int fn = 0; fn < 4; ++fn)
                acc[fm][fn] = __builtin_amdgcn_mfma_f32_16x16x32_f16(a_[fm], w_[fn], acc[fm][fn], 0, 0, 0);
        __syncthreads();
    }

    const int crow = (lane >> 4) * 4, ccol = lane & 15;
    #pragma unroll
    for (int fm = 0; fm < 4; ++fm)
        #pragma unroll
        for (int fn = 0; fn < 4; ++fn)
            #pragma unroll
            for (int j = 0; j < 4; ++j) {
                const int rl = wm + fm * 16 + crow + j;
                bxh[(m0 + rl) * 256 + n0 + wn + fn * 16 + ccol] =
                    f2h(acc[fm][fn][j] * sDtM[rl]);
            }
}

// ---------------------------------------------------------------------------
// Kernel 4: single-pass chunked scan with decoupled lookback.
// Block = (ticket-assigned chunk c, bg). Dead tile -> return (h never read).
// Dead-g in alive tile -> h=0 (exact value the full math would produce).
// Alive: local 32-step scan -> publish total -> sum alive predecessors
// (death monotone => all predecessors published) -> re-run loop emitting h.
// ---------------------------------------------------------------------------
__global__ __launch_bounds__(128) void scan_fused(
    u16* __restrict__ bxh,
    const double* __restrict__ cumM, const double* __restrict__ cumP,
    const float* __restrict__ logAmag, const float* __restrict__ Aphase,
    const u8* __restrict__ aliveF, const u32* __restrict__ aliveT,
    u32* __restrict__ Tc2, u32* __restrict__ flags, u32* __restrict__ ticket)
{
    const int bg = blockIdx.y, b = bg >> 2, g = bg & 3;
    const int n = threadIdx.x;
    __shared__ u32 smyc;
    if (n == 0) smyc = atomicAdd(&ticket[bg], 1u);
    __syncthreads();
    const int c = (int)smyc;
    if (aliveT[b * CHUNKS + c] == 0) return;

    const int s0 = c * CLEN;
    if (aliveF[(size_t)(b * CHUNKS + c) * 4 + g] == 0) {
        #pragma unroll 4
        for (int j = 0; j < CLEN; ++j) {
            const size_t tok = ((size_t)(b * Sdim + s0 + j)) * Gdim + g;
            bxh[tok * 256 + n]       = 0;
            bxh[tok * 256 + 128 + n] = 0;
        }
        return;
    }

    const double nlAd = (double)(-log1pf(expf(logAmag[g * Ndim + n])));
    const double aphd = (double)(Aphase[g * Ndim + n]);

    // pass A: local chunk total
    float Sr = 0.0f, Si = 0.0f;
    #pragma unroll 2
    for (int j = 0; j < CLEN; ++j) {
        const size_t tok = ((size_t)(b * Sdim + s0 + j)) * Gdim + g;
        const float clr = (float)(nlAd * cumM[tok]);
        const float cli = (float)(aphd * cumP[tok]);
        const float e = expf(clr);
        float sn, cs;
        sincosf(cli, &sn, &cs);
        const float car = e * cs, cai = e * sn;
        const float dr = car + 1e-12f, di = cai;
        const float inv = 1.0f / (dr * dr + di * di);
        const float bxr = h2f(bxh[tok * 256 + n]);
        const float bxi = h2f(bxh[tok * 256 + 128 + n]);
        Sr += (bxr * dr + bxi * di) * inv;
        Si += (bxi * dr - bxr * di) * inv;
    }

    // publish local total (relaxed atomics bypass L1), then release flag
    const size_t tbase = ((size_t)c * NCHAN + (size_t)bg * Ndim + n) * 2;
    __hip_atomic_store(&Tc2[tbase],     __float_as_uint(Sr), __ATOMIC_RELAXED, __HIP_MEMORY_SCOPE_AGENT);
    __hip_atomic_store(&Tc2[tbase + 1], __float_as_uint(Si), __ATOMIC_RELAXED, __HIP_MEMORY_SCOPE_AGENT);
    __syncthreads();
    if (n == 0)
        __hip_atomic_store(&flags[c * 16 + bg], 1u, __ATOMIC_RELEASE, __HIP_MEMORY_SCOPE_AGENT);

    // lookback: sum all predecessors' totals (all alive & published)
    float Pr = 0.0f, Pi = 0.0f;
    for (int cp = 0; cp < c; ++cp) {
        if (n == 0) {
            while (__hip_atomic_load(&flags[cp * 16 + bg], __ATOMIC_ACQUIRE,
                                     __HIP_MEMORY_SCOPE_AGENT) == 0) {}
        }
        __syncthreads();
        const size_t pb = ((size_t)cp * NCHAN + (size_t)bg * Ndim + n) * 2;
        Pr += __uint_as_float(__hip_atomic_load(&Tc2[pb],     __ATOMIC_RELAXED, __HIP_MEMORY_SCOPE_AGENT));
        Pi += __uint_as_float(__hip_atomic_load(&Tc2[pb + 1], __ATOMIC_RELAXED, __HIP_MEMORY_SCOPE_AGENT));
    }

    // pass B: emit clipped h with prefix
    Sr = Pr; Si = Pi;
    #pragma unroll 2
    for (int j = 0; j < CLEN; ++j) {
        const size_t tok = ((size_t)(b * Sdim + s0 + j)) * Gdim + g;
        const float clr = (float)(nlAd * cumM[tok]);
        const float cli = (float)(aphd * cumP[tok]);
        const float e = expf(clr);
        float sn, cs;
        sincosf(cli, &sn, &cs);
        const float car = e * cs, cai = e * sn;
        const float dr = car + 1e-12f, di = cai;
        const float inv = 1.0f / (dr * dr + di * di);
        const float bxr = h2f(bxh[tok * 256 + n]);
        const float bxi = h2f(bxh[tok * 256 + 128 + n]);
        Sr += (bxr * dr + bxi * di) * inv;
        Si += (bxi * dr - bxr * di) * inv;
        const float hr  = car * Sr - cai * Si;
        const float hi2 = car * Si + cai * Sr;
        const float nrm = sqrtf(hr * hr + hi2 * hi2 + 1e-8f);
        const float scl = fminf(nrm, 100.0f) / nrm;
        bxh[tok * 256 + n]       = f2h(hr * scl);
        bxh[tok * 256 + 128 + n] = f2h(hi2 * scl);
    }
}

// ---------------------------------------------------------------------------
// Kernel 5: GEMM 2 (MFMA f16): out = h . Wy^T (alive tiles only; out
// pre-zeroed by kernel 1, dead blocks return immediately).
// ---------------------------------------------------------------------------
__global__ __launch_bounds__(256) void gemm_y_mfma(
    const u16* __restrict__ Hp,
    const u16* __restrict__ Wh,
    const u32* __restrict__ aliveT,
    float* __restrict__ Cout)
{
    const int i0 = blockIdx.x;                       // 0..2047
    const int wg = (i0 & 7) * 256 + (i0 >> 3);       // bijective XCD chunking
    if (aliveT[wg >> 2] == 0) return;

    __shared__ u16 sA[128 * 32], sWh[128 * 32];
    const int tid = threadIdx.x, wave = tid >> 6, lane = tid & 63;
    const size_t m0 = (size_t)(wg >> 2) * 128;
    const int n0 = (wg & 3) * 128;
    const int wm = (wave >> 1) * 64, wn = (wave & 1) * 64;
    f32x4 acc[4][4] = {};
    const int srow = lane >> 2, pslot = lane & 3;

    #pragma unroll 1
    for (int k0 = 0; k0 < 256; k0 += 32) {
        #pragma unroll
        for (int i = 0; i < 2; ++i) {
            const int row = wave * 32 + i * 16 + srow;
            const int lslot = pslot ^ ((row >> 1) & 3);
            const int ldsoff = row * 32 + pslot * 8;
            gl_lds16(Hp + (m0 + row) * 256 + k0 + lslot * 8, sA + ldsoff);
            gl_lds16(Wh + (size_t)(n0 + row) * 256 + k0 + lslot * 8, sWh + ldsoff);
        }
        __syncthreads();

        const int fr = lane & 15, fs = lane >> 4;
        f16x8 a_[4], w_[4];
        #pragma unroll
        for (int f = 0; f < 4; ++f) {
            const int ra = wm + f * 16 + fr;
            a_[f] = *(const f16x8*)&sA [ra * 32 + (fs ^ ((ra >> 1) & 3)) * 8];
            const int rw = wn + f * 16 + fr;
            w_[f] = *(const f16x8*)&sWh[rw * 32 + (fs ^ ((rw >> 1) & 3)) * 8];
        }
        #pragma unroll
        for (int fm = 0; fm < 4; ++fm)
            #pragma unroll
            for (int fn = 0; fn < 4; ++fn)
                acc[fm][fn] = __builtin_amdgcn_mfma_f32_16x16x32_f16(a_[fm], w_[fn], acc[fm][fn], 0, 0, 0);
        __syncthreads();
    }

    const int crow = (lane >> 4) * 4, ccol = lane & 15;
    #pragma unroll
    for (int fm = 0; fm < 4; ++fm)
        #pragma unroll
        for (int fn = 0; fn < 4; ++fn)
            #pragma unroll
            for (int j = 0; j < 4; ++j)
                Cout[(m0 + wm + fm * 16 + crow + j) * 512 + n0 + wn + fn * 16 + ccol] =
                    acc[fm][fn][j];
}

// ---------------------------------------------------------------------------
extern "C" void kernel_launch(void* const* d_in, const int* in_sizes, int n_in,
                              void* d_out, int out_size, void* d_ws, size_t ws_size,
                              hipStream_t stream)
{
    const float* xr      = (const float*)d_in[0];
    const float* xi      = (const float*)d_in[1];
    const float* logAmag = (const float*)d_in[2];
    const float* Aphase  = (const float*)d_in[3];
    const float* Bwr     = (const float*)d_in[4];
    const float* Bwi     = (const float*)d_in[5];
    const float* Cwr     = (const float*)d_in[6];
    const float* Cwi     = (const float*)d_in[7];
    const float* dtw     = (const float*)d_in[8];
    const float* dtb     = (const float*)d_in[9];
    float* out = (float*)d_out;

    char* ws = (char*)d_ws;
    size_t off = 0;
    u16* bxh  = (u16*)(ws + off);  off += (size_t)NTOK * 256 * sizeof(u16);  // 32 MiB
    float* dtm = (float*)(ws + off);  off += (size_t)NTOK * sizeof(float);
    float* dtp = (float*)(ws + off);  off += (size_t)NTOK * sizeof(float);
    double* cumM = (double*)(ws + off); off += (size_t)NTOK * sizeof(double);
    double* cumP = (double*)(ws + off); off += (size_t)NTOK * sizeof(double);
    u32* Tc2 = (u32*)(ws + off); off += (size_t)CHUNKS * NCHAN * 2 * sizeof(u32);
    u16* WbxH = (u16*)(ws + off); off += 256 * 512 * sizeof(u16);
    u16* WyH  = (u16*)(ws + off); off += 512 * 256 * sizeof(u16);
    u8* aliveF = (u8*)(ws + off); off += NTILE * 4;
    u32* flags = (u32*)(ws + off); off += CHUNKS * 16 * sizeof(u32);
    u32* ticket = (u32*)(ws + off); off += 16 * sizeof(u32);

    dt_prep_zero<<<16896, 256, 0, stream>>>(xr, xi, dtw, dtb, Bwr, Bwi, Cwr, Cwi,
                                            dtm, dtp, WbxH, WyH, out);
    cumsum_kernel<<<Bdim * Gdim, 256, 0, stream>>>(dtm, dtp, logAmag, cumM, cumP,
                                                   aliveF, flags, ticket);
    gemm_bx_mfma<<<1024, 256, 0, stream>>>(xr, xi, WbxH, dtm, (const u32*)aliveF, bxh);
    scan_fused<<<dim3(CHUNKS, Bdim * Gdim), 128, 0, stream>>>(
        bxh, cumM, cumP, logAmag, Aphase, aliveF, (const u32*)aliveF,
        Tc2, flags, ticket);
    gemm_y_mfma<<<2048, 256, 0, stream>>>(bxh, WyH, (const u32*)aliveF, out);
}

// Round 8
// 104.164 us; speedup vs baseline: 1.3847x; 1.3847x over previous
//
#include <hip/hip_runtime.h>
#include <math.h>

#define Bdim 4
#define Sdim 4096
#define Gdim 4
#define Ddim 256
#define Ndim 128
#define NTOK (Bdim*Sdim*Gdim)      // 65536 tokens
#define CHUNKS 128
#define CLEN (Sdim/CHUNKS)         // 32 steps per chunk == M-tile s-span
#define NCHAN (Bdim*Gdim*Ndim)     // 2048 scan channels
#define NTILE (Bdim*CHUNKS)        // 512 M-tiles of 128 tokens
#define SEARLY 256                 // dt precomputed for s < SEARLY

typedef unsigned short u16;
typedef unsigned int   u32;
typedef unsigned char  u8;
typedef __attribute__((ext_vector_type(8))) _Float16 f16x8;
typedef __attribute__((ext_vector_type(4))) _Float16 f16x4;
typedef __attribute__((ext_vector_type(4))) float f32x4;

#define GLOBAL_AS __attribute__((address_space(1)))
#define LDS_AS    __attribute__((address_space(3)))

__device__ __forceinline__ void gl_lds16(const void* g, void* l) {
    __builtin_amdgcn_global_load_lds((const GLOBAL_AS u32*)g, (LDS_AS u32*)l, 16, 0, 0);
}

union HU { _Float16 h; u16 u; };
__device__ __forceinline__ u16 f2h(float f) { HU c; c.h = (_Float16)f; return c.u; }
__device__ __forceinline__ float h2f(u16 u) { HU c; c.u = u; return (float)c.h; }

// ---------------------------------------------------------------------------
// Kernel 1: dt projection for s < SEARLY (one wave/token) + f16 weight prep.
// Blocks [0,1024): dt. Blocks [1024,1536): weight prep.
// ---------------------------------------------------------------------------
__global__ __launch_bounds__(256) void dt_early_prep(
    const float* __restrict__ xr, const float* __restrict__ xi,
    const float* __restrict__ dtw, const float* __restrict__ dtb,
    const float* __restrict__ Bwr, const float* __restrict__ Bwi,
    const float* __restrict__ Cwr, const float* __restrict__ Cwi,
    float* __restrict__ dtm, float* __restrict__ dtp,
    u16* __restrict__ WbxH, u16* __restrict__ WyH)
{
    const int tid = threadIdx.x;
    if (blockIdx.x >= 1024) {                        // weight prep
        const int idx = (blockIdx.x - 1024) * 256 + tid;   // 0..131071
        {
            const int n = idx >> 9, k = idx & 511;
            float v;
            if (n < 128) v = (k < 256) ? Bwr[n * 256 + k] : -Bwi[n * 256 + (k - 256)];
            else         v = (k < 256) ? Bwi[(n - 128) * 256 + k] : Bwr[(n - 128) * 256 + (k - 256)];
            WbxH[idx] = f2h(v);
        }
        {
            const int d = idx >> 8, k = idx & 255;
            float v;
            if (d < 256) v = (k < 128) ? Cwr[d * 128 + k] : -Cwi[d * 128 + (k - 128)];
            else         v = (k < 128) ? Cwi[(d - 256) * 128 + k] : Cwr[(d - 256) * 128 + (k - 128)];
            WyH[idx] = f2h(v);
        }
        return;
    }

    const int gtid = blockIdx.x * 256 + tid;
    const int w = gtid >> 6;                         // 0..4095 early waves
    const int lane = gtid & 63;
    const int b = w >> 10, s = (w >> 2) & 255, g = w & 3;
    const size_t tok = ((size_t)(b * Sdim + s)) * Gdim + g;

    const float4 a  = *(const float4*)(xr  + tok * Ddim + lane * 4);
    const float4 b4 = *(const float4*)(xi  + tok * Ddim + lane * 4);
    const float4 c0 = *(const float4*)(dtw +   0 + lane * 4);
    const float4 d0 = *(const float4*)(dtw + 256 + lane * 4);
    const float4 c1 = *(const float4*)(dtw + 512 + lane * 4);
    const float4 d1 = *(const float4*)(dtw + 768 + lane * 4);

    float r0 = a.x*c0.x + a.y*c0.y + a.z*c0.z + a.w*c0.w
             + b4.x*d0.x + b4.y*d0.y + b4.z*d0.z + b4.w*d0.w;
    float r1 = a.x*c1.x + a.y*c1.y + a.z*c1.z + a.w*c1.w
             + b4.x*d1.x + b4.y*d1.y + b4.z*d1.z + b4.w*d1.w;
    #pragma unroll
    for (int off = 32; off; off >>= 1) {
        r0 += __shfl_down(r0, off);
        r1 += __shfl_down(r1, off);
    }
    if (lane == 0) {
        float m = expf(r0 + dtb[0]); m = fminf(fmaxf(m, 1e-4f), 2.0f);
        float p = expf(r1 + dtb[1]); p = fminf(fmaxf(p, 1e-4f), 2.0f);
        dtm[tok] = m;
        dtp[tok] = p;
    }
}

// ---------------------------------------------------------------------------
// Kernel 2: per-(b,g) cumsum + alive flags + scan flag/ticket reset.
// Fast path: scan s<256 (one token/thread); if dead by s=255 (monotone cumM
// guarantees all later chunks dead) zero remaining flags and exit.
// Fallback (correctness only, never taken on typical data): compute dt for
// s>=256 in-kernel (15 tokens/thread) and continue the f64 scan with carry.
// ---------------------------------------------------------------------------
__global__ __launch_bounds__(256) void cumsum_all(
    const float* __restrict__ xr, const float* __restrict__ xi,
    const float* __restrict__ dtw, const float* __restrict__ dtb,
    const float* __restrict__ logAmag,
    float* __restrict__ dtm, float* __restrict__ dtp,
    double* __restrict__ cumM, double* __restrict__ cumP,
    u8* __restrict__ aliveF, u32* __restrict__ flags, u32* __restrict__ ticket)
{
    const int bg = blockIdx.x, b = bg >> 2, g = bg & 3;
    const int t = threadIdx.x, lane = t & 63, wid = t >> 6;

    if (t < CHUNKS) flags[t * 16 + bg] = 0;          // reset lookback state
    if (t == 128)   ticket[bg] = 0;

    // min_n softplus(log_A_mag[g,n])
    __shared__ float sws[4];
    float spv = 1e30f;
    if (t < 128) spv = log1pf(expf(logAmag[g * Ndim + t]));
    #pragma unroll
    for (int off = 32; off; off >>= 1) spv = fminf(spv, __shfl_down(spv, off));
    if (lane == 0) sws[wid] = spv;
    __syncthreads();
    const double minsp = (double)fminf(fminf(sws[0], sws[1]), fminf(sws[2], sws[3]));

    const size_t base = (size_t)b * Sdim * Gdim + g;
    __shared__ double wtm[4], wtp[4];

    // ---- early inclusive scan: one token per thread (s = t < 256)
    const size_t tokE = base + (size_t)t * Gdim;
    double im = (double)dtm[tokE], ip = (double)dtp[tokE];
    #pragma unroll
    for (int off = 1; off < 64; off <<= 1) {
        double um = __shfl_up(im, off);
        double up = __shfl_up(ip, off);
        if (lane >= off) { im += um; ip += up; }
    }
    __syncthreads();
    if (lane == 63) { wtm[wid] = im; wtp[wid] = ip; }
    __syncthreads();
    for (int w = 0; w < wid; ++w) { im += wtm[w]; ip += wtp[w]; }
    cumM[tokE] = im;
    cumP[tokE] = ip;
    if ((t & 31) == 0)                               // chunk starts s=32c, c<8
        aliveF[(size_t)(b * CHUNKS + (t >> 5)) * 4 + g] =
            (minsp * im <= 106.0) ? 1 : 0;

    __shared__ double stot[2];
    if (t == 255) { stot[0] = im; stot[1] = ip; }
    __syncthreads();
    const bool dead = (minsp * stot[0] > 106.0);

    if (dead) {                                      // fast path: done
        for (int c = 8 + t; c < CHUNKS; c += 256)
            aliveF[(size_t)(b * CHUNKS + c) * 4 + g] = 0;
        return;
    }

    // ---- FALLBACK: dt + scan for s >= 256 (15 tokens/thread)
    const int sbeg = SEARLY + t * 15;
    double lm[15], lp[15], sm = 0.0, sp2 = 0.0;
    #pragma unroll 1
    for (int j = 0; j < 15; ++j) {
        const size_t tok = base + (size_t)(sbeg + j) * Gdim;
        float r0 = 0.f, r1 = 0.f;
        for (int k = 0; k < 256; k += 4) {
            const float4 va = *(const float4*)(xr + tok * Ddim + k);
            const float4 vb = *(const float4*)(xi + tok * Ddim + k);
            const float4 c0 = *(const float4*)(dtw + k);
            const float4 d0 = *(const float4*)(dtw + 256 + k);
            const float4 c1 = *(const float4*)(dtw + 512 + k);
            const float4 d1 = *(const float4*)(dtw + 768 + k);
            r0 += va.x*c0.x + va.y*c0.y + va.z*c0.z + va.w*c0.w
                + vb.x*d0.x + vb.y*d0.y + vb.z*d0.z + vb.w*d0.w;
            r1 += va.x*c1.x + va.y*c1.y + va.z*c1.z + va.w*c1.w
                + vb.x*d1.x + vb.y*d1.y + vb.z*d1.z + vb.w*d1.w;
        }
        float m = expf(r0 + dtb[0]); m = fminf(fmaxf(m, 1e-4f), 2.0f);
        float p = expf(r1 + dtb[1]); p = fminf(fmaxf(p, 1e-4f), 2.0f);
        dtm[tok] = m; dtp[tok] = p;
        sm += (double)m; lm[j] = sm;
        sp2 += (double)p; lp[j] = sp2;
    }
    double jm = sm, jp = sp2;
    #pragma unroll
    for (int off = 1; off < 64; off <<= 1) {
        double um = __shfl_up(jm, off);
        double up = __shfl_up(jp, off);
        if (lane >= off) { jm += um; jp += up; }
    }
    __syncthreads();
    if (lane == 63) { wtm[wid] = jm; wtp[wid] = jp; }
    __syncthreads();
    double bm = jm - sm, bp = jp - sp2;
    for (int w = 0; w < wid; ++w) { bm += wtm[w]; bp += wtp[w]; }
    bm += stot[0]; bp += stot[1];                    // carry from early region
    #pragma unroll 1
    for (int j = 0; j < 15; ++j) {
        const int s = sbeg + j;
        const size_t tok = base + (size_t)s * Gdim;
        const double cm = bm + lm[j];
        cumM[tok] = cm;
        cumP[tok] = bp + lp[j];
        if ((s & 31) == 0)
            aliveF[(size_t)(b * CHUNKS + (s >> 5)) * 4 + g] =
                (minsp * cm <= 106.0) ? 1 : 0;
    }
}

// ---------------------------------------------------------------------------
// Kernel 3: GEMM 1 (MFMA f16): bx = (xcat . Wbx^T) * dt_mag  (f16, alive only)
// ---------------------------------------------------------------------------
__global__ __launch_bounds__(256) void gemm_bx_mfma(
    const float* __restrict__ xr, const float* __restrict__ xi,
    const u16* __restrict__ Wh, const float* __restrict__ dtm,
    const u32* __restrict__ aliveT,
    u16* __restrict__ bxh)
{
    const int i0 = blockIdx.x;                       // 0..1023
    const int wg = (i0 & 7) * 128 + (i0 >> 3);       // bijective XCD chunking
    if (aliveT[wg >> 1] == 0) return;

    __shared__ u16 sA[128 * 32], sWh[128 * 32];
    __shared__ float sDtM[128];
    const int tid = threadIdx.x, wave = tid >> 6, lane = tid & 63;
    const size_t m0 = (size_t)(wg >> 1) * 128;
    const int n0 = (wg & 1) * 128;
    const int wm = (wave >> 1) * 64, wn = (wave & 1) * 64;
    f32x4 acc[4][4] = {};
    const int srow = lane >> 2, pslot = lane & 3;

    if (tid < 128) sDtM[tid] = dtm[m0 + tid];

    const int arow = tid >> 3;            // 0..31
    const int acol = (tid & 7) * 4;       // 0..28 within 32-col window
    const int asl  = acol >> 3;
    const int asub = acol & 7;

    #pragma unroll 1
    for (int k0 = 0; k0 < 512; k0 += 32) {
        {   // A: coalesced fp32 load -> f16 ds_write (swizzled)
            const float* xsrc = (k0 < 256) ? xr : xi;
            const int kk = (k0 & 255) + acol;
            #pragma unroll
            for (int i = 0; i < 4; ++i) {
                const int row = arow + 32 * i;
                const float4 v = *(const float4*)(xsrc + (m0 + row) * 256 + kk);
                f16x4 p;
                p[0] = (_Float16)v.x; p[1] = (_Float16)v.y;
                p[2] = (_Float16)v.z; p[3] = (_Float16)v.w;
                *(f16x4*)&sA[row * 32 + (asl ^ ((row >> 1) & 3)) * 8 + asub] = p;
            }
        }
        #pragma unroll
        for (int i = 0; i < 2; ++i) {                // W via global_load_lds
            const int row = wave * 32 + i * 16 + srow;
            const int lslot = pslot ^ ((row >> 1) & 3);
            gl_lds16(Wh + (size_t)(n0 + row) * 512 + k0 + lslot * 8,
                     sWh + row * 32 + pslot * 8);
        }
        __syncthreads();

        const int fr = lane & 15, fs = lane >> 4;
        f16x8 a_[4], w_[4];
        #pragma unroll
        for (int f = 0; f < 4; ++f) {
            const int ra = wm + f * 16 + fr;
            a_[f] = *(const f16x8*)&sA [ra * 32 + (fs ^ ((ra >> 1) & 3)) * 8];
            const int rw = wn + f * 16 + fr;
            w_[f] = *(const f16x8*)&sWh[rw * 32 + (fs ^ ((rw >> 1) & 3)) * 8];
        }
        #pragma unroll
        for (int fm = 0; fm < 4; ++fm)
            #pragma unroll
            for (int fn = 0; fn < 4; ++fn)
                acc[fm][fn] = __builtin_amdgcn_mfma_f32_16x16x32_f16(a_[fm], w_[fn], acc[fm][fn], 0, 0, 0);
        __syncthreads();
    }

    const int crow = (lane >> 4) * 4, ccol = lane & 15;
    #pragma unroll
    for (int fm = 0; fm < 4; ++fm)
        #pragma unroll
        for (int fn = 0; fn < 4; ++fn)
            #pragma unroll
            for (int j = 0; j < 4; ++j) {
                const int rl = wm + fm * 16 + crow + j;
                bxh[(m0 + rl) * 256 + n0 + wn + fn * 16 + ccol] =
                    f2h(acc[fm][fn][j] * sDtM[rl]);
            }
}

// ---------------------------------------------------------------------------
// Kernel 4: single-pass chunked scan with decoupled lookback (ticketed).
// ---------------------------------------------------------------------------
__global__ __launch_bounds__(128) void scan_fused(
    u16* __restrict__ bxh,
    const double* __restrict__ cumM, const double* __restrict__ cumP,
    const float* __restrict__ logAmag, const float* __restrict__ Aphase,
    const u8* __restrict__ aliveF, const u32* __restrict__ aliveT,
    u32* __restrict__ Tc2, u32* __restrict__ flags, u32* __restrict__ ticket)
{
    const int bg = blockIdx.y, b = bg >> 2, g = bg & 3;
    const int n = threadIdx.x;
    __shared__ u32 smyc;
    if (n == 0) smyc = atomicAdd(&ticket[bg], 1u);
    __syncthreads();
    const int c = (int)smyc;
    if (aliveT[b * CHUNKS + c] == 0) return;

    const int s0 = c * CLEN;
    if (aliveF[(size_t)(b * CHUNKS + c) * 4 + g] == 0) {
        #pragma unroll 4
        for (int j = 0; j < CLEN; ++j) {
            const size_t tok = ((size_t)(b * Sdim + s0 + j)) * Gdim + g;
            bxh[tok * 256 + n]       = 0;
            bxh[tok * 256 + 128 + n] = 0;
        }
        return;
    }

    const double nlAd = (double)(-log1pf(expf(logAmag[g * Ndim + n])));
    const double aphd = (double)(Aphase[g * Ndim + n]);

    // pass A: local chunk total
    float Sr = 0.0f, Si = 0.0f;
    #pragma unroll 2
    for (int j = 0; j < CLEN; ++j) {
        const size_t tok = ((size_t)(b * Sdim + s0 + j)) * Gdim + g;
        const float clr = (float)(nlAd * cumM[tok]);
        const float cli = (float)(aphd * cumP[tok]);
        const float e = expf(clr);
        float sn, cs;
        sincosf(cli, &sn, &cs);
        const float car = e * cs, cai = e * sn;
        const float dr = car + 1e-12f, di = cai;
        const float inv = 1.0f / (dr * dr + di * di);
        const float bxr = h2f(bxh[tok * 256 + n]);
        const float bxi = h2f(bxh[tok * 256 + 128 + n]);
        Sr += (bxr * dr + bxi * di) * inv;
        Si += (bxi * dr - bxr * di) * inv;
    }

    const size_t tbase = ((size_t)c * NCHAN + (size_t)bg * Ndim + n) * 2;
    __hip_atomic_store(&Tc2[tbase],     __float_as_uint(Sr), __ATOMIC_RELAXED, __HIP_MEMORY_SCOPE_AGENT);
    __hip_atomic_store(&Tc2[tbase + 1], __float_as_uint(Si), __ATOMIC_RELAXED, __HIP_MEMORY_SCOPE_AGENT);
    __syncthreads();
    if (n == 0)
        __hip_atomic_store(&flags[c * 16 + bg], 1u, __ATOMIC_RELEASE, __HIP_MEMORY_SCOPE_AGENT);

    // lookback: sum predecessors (all alive & will publish; co-resident grid)
    float Pr = 0.0f, Pi = 0.0f;
    for (int cp = 0; cp < c; ++cp) {
        if (n == 0) {
            while (__hip_atomic_load(&flags[cp * 16 + bg], __ATOMIC_ACQUIRE,
                                     __HIP_MEMORY_SCOPE_AGENT) == 0) {}
        }
        __syncthreads();
        const size_t pb = ((size_t)cp * NCHAN + (size_t)bg * Ndim + n) * 2;
        Pr += __uint_as_float(__hip_atomic_load(&Tc2[pb],     __ATOMIC_RELAXED, __HIP_MEMORY_SCOPE_AGENT));
        Pi += __uint_as_float(__hip_atomic_load(&Tc2[pb + 1], __ATOMIC_RELAXED, __HIP_MEMORY_SCOPE_AGENT));
    }

    // pass B: emit clipped h with prefix
    Sr = Pr; Si = Pi;
    #pragma unroll 2
    for (int j = 0; j < CLEN; ++j) {
        const size_t tok = ((size_t)(b * Sdim + s0 + j)) * Gdim + g;
        const float clr = (float)(nlAd * cumM[tok]);
        const float cli = (float)(aphd * cumP[tok]);
        const float e = expf(clr);
        float sn, cs;
        sincosf(cli, &sn, &cs);
        const float car = e * cs, cai = e * sn;
        const float dr = car + 1e-12f, di = cai;
        const float inv = 1.0f / (dr * dr + di * di);
        const float bxr = h2f(bxh[tok * 256 + n]);
        const float bxi = h2f(bxh[tok * 256 + 128 + n]);
        Sr += (bxr * dr + bxi * di) * inv;
        Si += (bxi * dr - bxr * di) * inv;
        const float hr  = car * Sr - cai * Si;
        const float hi2 = car * Si + cai * Sr;
        const float nrm = sqrtf(hr * hr + hi2 * hi2 + 1e-8f);
        const float scl = fminf(nrm, 100.0f) / nrm;
        bxh[tok * 256 + n]       = f2h(hr * scl);
        bxh[tok * 256 + 128 + n] = f2h(hi2 * scl);
    }
}

// ---------------------------------------------------------------------------
// Kernel 5: GEMM 2 (MFMA f16): out = h . Wy^T; dead tiles write zeros.
// ---------------------------------------------------------------------------
__global__ __launch_bounds__(256) void gemm_y_mfma(
    const u16* __restrict__ Hp,
    const u16* __restrict__ Wh,
    const u32* __restrict__ aliveT,
    float* __restrict__ Cout)
{
    const int tid = threadIdx.x;
    const int i0 = blockIdx.x;                       // 0..2047
    const int wg = (i0 & 7) * 256 + (i0 >> 3);       // bijective XCD chunking
    const size_t m0 = (size_t)(wg >> 2) * 128;
    const int n0 = (wg & 3) * 128;

    if (aliveT[wg >> 2] == 0) {                      // dead tile -> zero-fill
        const float4 z = make_float4(0.f, 0.f, 0.f, 0.f);
        #pragma unroll
        for (int it = 0; it < 16; ++it) {
            const int row = it * 8 + (tid >> 5);
            *(float4*)&Cout[(m0 + row) * 512 + n0 + (tid & 31) * 4] = z;
        }
        return;
    }

    __shared__ u16 sA[128 * 32], sWh[128 * 32];
    const int wave = tid >> 6, lane = tid & 63;
    const int wm = (wave >> 1) * 64, wn = (wave & 1) * 64;
    f32x4 acc[4][4] = {};
    const int srow = lane >> 2, pslot = lane & 3;

    #pragma unroll 1
    for (int k0 = 0; k0 < 256; k0 += 32) {
        #pragma unroll
        for (int i = 0; i < 2; ++i) {
            const int row = wave * 32 + i * 16 + srow;
            const int lslot = pslot ^ ((row >> 1) & 3);
            const int ldsoff = row * 32 + pslot * 8;
            gl_lds16(Hp + (m0 + row) * 256 + k0 + lslot * 8, sA + ldsoff);
            gl_lds16(Wh + (size_t)(n0 + row) * 256 + k0 + lslot * 8, sWh + ldsoff);
        }
        __syncthreads();

        const int fr = lane & 15, fs = lane >> 4;
        f16x8 a_[4], w_[4];
        #pragma unroll
        for (int f = 0; f < 4; ++f) {
            const int ra = wm + f * 16 + fr;
            a_[f] = *(const f16x8*)&sA [ra * 32 + (fs ^ ((ra >> 1) & 3)) * 8];
            const int rw = wn + f * 16 + fr;
            w_[f] = *(const f16x8*)&sWh[rw * 32 + (fs ^ ((rw >> 1) & 3)) * 8];
        }
        #pragma unroll
        for (int fm = 0; fm < 4; ++fm)
            #pragma unroll
            for (int fn = 0; fn < 4; ++fn)
                acc[fm][fn] = __builtin_amdgcn_mfma_f32_16x16x32_f16(a_[fm], w_[fn], acc[fm][fn], 0, 0, 0);
        __syncthreads();
    }

    const int crow = (lane >> 4) * 4, ccol = lane & 15;
    #pragma unroll
    for (int fm = 0; fm < 4; ++fm)
        #pragma unroll
        for (int fn = 0; fn < 4; ++fn)
            #pragma unroll
            for (int j = 0; j < 4; ++j)
                Cout[(m0 + wm + fm * 16 + crow + j) * 512 + n0 + wn + fn * 16 + ccol] =
                    acc[fm][fn][j];
}

// ---------------------------------------------------------------------------
extern "C" void kernel_launch(void* const* d_in, const int* in_sizes, int n_in,
                              void* d_out, int out_size, void* d_ws, size_t ws_size,
                              hipStream_t stream)
{
    const float* xr      = (const float*)d_in[0];
    const float* xi      = (const float*)d_in[1];
    const float* logAmag = (const float*)d_in[2];
    const float* Aphase  = (const float*)d_in[3];
    const float* Bwr     = (const float*)d_in[4];
    const float* Bwi     = (const float*)d_in[5];
    const float* Cwr     = (const float*)d_in[6];
    const float* Cwi     = (const float*)d_in[7];
    const float* dtw     = (const float*)d_in[8];
    const float* dtb     = (const float*)d_in[9];
    float* out = (float*)d_out;

    char* ws = (char*)d_ws;
    size_t off = 0;
    u16* bxh  = (u16*)(ws + off);  off += (size_t)NTOK * 256 * sizeof(u16);  // 32 MiB
    float* dtm = (float*)(ws + off);  off += (size_t)NTOK * sizeof(float);
    float* dtp = (float*)(ws + off);  off += (size_t)NTOK * sizeof(float);
    double* cumM = (double*)(ws + off); off += (size_t)NTOK * sizeof(double);
    double* cumP = (double*)(ws + off); off += (size_t)NTOK * sizeof(double);
    u32* Tc2 = (u32*)(ws + off); off += (size_t)CHUNKS * NCHAN * 2 * sizeof(u32);
    u16* WbxH = (u16*)(ws + off); off += 256 * 512 * sizeof(u16);
    u16* WyH  = (u16*)(ws + off); off += 512 * 256 * sizeof(u16);
    u8* aliveF = (u8*)(ws + off); off += NTILE * 4;
    u32* flags = (u32*)(ws + off); off += CHUNKS * 16 * sizeof(u32);
    u32* ticket = (u32*)(ws + off); off += 16 * sizeof(u32);

    dt_early_prep<<<1536, 256, 0, stream>>>(xr, xi, dtw, dtb, Bwr, Bwi, Cwr, Cwi,
                                            dtm, dtp, WbxH, WyH);
    cumsum_all<<<Bdim * Gdim, 256, 0, stream>>>(xr, xi, dtw, dtb, logAmag,
                                                dtm, dtp, cumM, cumP,
                                                aliveF, flags, ticket);
    gemm_bx_mfma<<<1024, 256, 0, stream>>>(xr, xi, WbxH, dtm, (const u32*)aliveF, bxh);
    scan_fused<<<dim3(CHUNKS, Bdim * Gdim), 128, 0, stream>>>(
        bxh, cumM, cumP, logAmag, Aphase, aliveF, (const u32*)aliveF,
        Tc2, flags, ticket);
    gemm_y_mfma<<<2048, 256, 0, stream>>>(bxh, WyH, (const u32*)aliveF, out);
}